// Round 1
// baseline (135.218 us; speedup 1.0000x reference)
//
#include <hip/hip_runtime.h>

// GATraj fused kernel for MI355X (gfx950).
//
// Key simplifications derived from the reference math:
//  * LN over the size-1 W_a channel == be_a exactly -> Pos is uniform 1/cnt_i
//    over masked neighbors (exp(-10000) == 0 in f32). W_a/b_a/g_a unused.
//  * tmp @ W_g = r@Wg[0:64] + h_i@Wg[64:128] + h_j@Wg[128:192]; the latter two
//    are per-node precomputes (A_pre includes b_g).
//  * LN of (c0*w0 + c1*w1 + b_r) is analytic: mean/var are a quadratic form in
//    (c0,c1) with 6 precomputed moments of centered W_r columns.
//
// Main kernel: 1 block / row i, 256 threads (4 waves). Compact masked j list,
// chunks of 64 pairs: wave0 computes per-pair (c0,c1,invstd); each wave builds
// its 16 bf16 R-rows in LDS; 8x mfma_f32_16x16x32_bf16 vs register-resident
// Wg_lo fragments; epilogue does LN over d (shfl_xor within 16-lane groups),
// sigmoid, and accumulates gate*h[j]. Final (HSum@W_w -> LN -> relu) + cn,
// tanh, outputs fused into the same block.

#define NN 768
#define DD 64
#define EPSF 1e-5f

typedef __attribute__((ext_vector_type(8))) short short8;
typedef __attribute__((ext_vector_type(4))) float float4v;

__device__ __forceinline__ unsigned short f2bf(float f) {
  unsigned int u = __float_as_uint(f);
  u += 0x7fffu + ((u >> 16) & 1u);  // round-to-nearest-even
  return (unsigned short)(u >> 16);
}

// ---------------------------------------------------------------------------
// Prep: A_pre[i][d] = b_g[d] + h[i]@Wg[64:128];  B_pre[j][d] = h[j]@Wg[128:192]
// Block NN computes centered W_r columns + the 6 second moments for the
// analytic r-LayerNorm.
// ---------------------------------------------------------------------------
__global__ __launch_bounds__(64) void prep_kernel(
    const float* __restrict__ hidden, const float* __restrict__ Wg,
    const float* __restrict__ bg, const float* __restrict__ Wr,
    const float* __restrict__ br, float* __restrict__ A_pre,
    float* __restrict__ B_pre, float* __restrict__ w0h,
    float* __restrict__ w1h, float* __restrict__ bh,
    float* __restrict__ evec) {
  const int t = threadIdx.x;  // 0..63, == d
  const int i = blockIdx.x;
  if (i < NN) {
    float hv = hidden[i * DD + t];
    float a = bg[t];
    float b = 0.f;
#pragma unroll 8
    for (int k = 0; k < DD; ++k) {
      float hk = __shfl(hv, k);
      a = fmaf(hk, Wg[(DD + k) * DD + t], a);
      b = fmaf(hk, Wg[(2 * DD + k) * DD + t], b);
    }
    A_pre[i * DD + t] = a;
    B_pre[i * DD + t] = b;
  } else {
    float w0 = Wr[t], w1 = Wr[DD + t], bb = br[t];
    float m0 = w0, m1 = w1, mb = bb;
    for (int m = 1; m < 64; m <<= 1) {
      m0 += __shfl_xor(m0, m);
      m1 += __shfl_xor(m1, m);
      mb += __shfl_xor(mb, m);
    }
    m0 *= (1.f / DD);
    m1 *= (1.f / DD);
    mb *= (1.f / DD);
    float a0 = w0 - m0, a1 = w1 - m1, ab = bb - mb;
    w0h[t] = a0;
    w1h[t] = a1;
    bh[t] = ab;
    float e00 = a0 * a0, e11 = a1 * a1, ebb = ab * ab;
    float e01 = a0 * a1, e0b = a0 * ab, e1b = a1 * ab;
    for (int m = 1; m < 64; m <<= 1) {
      e00 += __shfl_xor(e00, m);
      e11 += __shfl_xor(e11, m);
      ebb += __shfl_xor(ebb, m);
      e01 += __shfl_xor(e01, m);
      e0b += __shfl_xor(e0b, m);
      e1b += __shfl_xor(e1b, m);
    }
    if (t == 0) {
      evec[0] = e00 * (1.f / DD);
      evec[1] = e11 * (1.f / DD);
      evec[2] = ebb * (1.f / DD);
      evec[3] = e01 * (1.f / DD);
      evec[4] = e0b * (1.f / DD);
      evec[5] = e1b * (1.f / DD);
    }
  }
}

// ---------------------------------------------------------------------------
// Main fused kernel: one block per row i.
// ---------------------------------------------------------------------------
__global__ __launch_bounds__(256) void gatraj_main(
    const float* __restrict__ corr, const int* __restrict__ nei,
    const float* __restrict__ hidden, const float* __restrict__ cn,
    const float* __restrict__ gr, const float* __restrict__ ber,
    const float* __restrict__ Wg, const float* __restrict__ gg,
    const float* __restrict__ beg, const float* __restrict__ bea,
    const float* __restrict__ Ww, const float* __restrict__ bw,
    const float* __restrict__ gw, const float* __restrict__ bew,
    const float* __restrict__ A_pre, const float* __restrict__ B_pre,
    const float* __restrict__ w0h, const float* __restrict__ w1h,
    const float* __restrict__ bh, const float* __restrict__ evec,
    float* __restrict__ out) {
  __shared__ __align__(16) unsigned short Rt[64 * 72];  // 64 pairs x 64 k, pad 8
  __shared__ short Lst[NN];
  __shared__ short jpc[64];
  __shared__ float4v cpk[64];  // {c0, c1, invstd, 0} per chunk pair
  __shared__ float red[4 * 64];
  __shared__ int cntLds;

  const int i = blockIdx.x;
  const int tid = threadIdx.x;
  const int wid = tid >> 6;
  const int lane = tid & 63;
  const int quad = lane >> 4;
  const int nl = lane & 15;

  if (tid == 0) cntLds = 0;
  __syncthreads();
  // Compact masked neighbor list (order-free: used for an unordered sum).
#pragma unroll
  for (int rep = 0; rep < 3; ++rep) {
    int jj = tid + rep * 256;
    if (nei[i * NN + jj] > 0) {
      int idx = atomicAdd(&cntLds, 1);
      Lst[idx] = (short)jj;
    }
  }

  // Per-lane constants for the r phase (lane == k), pre-scaled by g_r.
  const float pgr = gr[lane];
  const float gw0 = pgr * w0h[lane];
  const float gw1 = pgr * w1h[lane];
  const float gbh = pgr * bh[lane];
  const float pber = ber[lane];
  const float e00 = evec[0], e11 = evec[1], ebb = evec[2];
  const float e01 = evec[3], e0b = evec[4], e1b = evec[5];

  // Epilogue per-lane constants: d = nt*16 + nl.
  float gg4[4], beg4[4], pre4[4];
#pragma unroll
  for (int nt = 0; nt < 4; ++nt) {
    int d = nt * 16 + nl;
    gg4[nt] = gg[d];
    beg4[nt] = beg[d];
    pre4[nt] = A_pre[i * DD + d];
  }

  // B fragments of Wg_lo (rows 0..63), resident in registers.
  // B[k][n]: n = nt*16 + nl, k = ks*32 + quad*8 + e.
  short8 Bf[2][4];
#pragma unroll
  for (int ks = 0; ks < 2; ++ks)
#pragma unroll
    for (int nt = 0; nt < 4; ++nt) {
      short8 f;
#pragma unroll
      for (int e = 0; e < 8; ++e) {
        int k = ks * 32 + quad * 8 + e;
        f[e] = (short)f2bf(Wg[k * DD + nt * 16 + nl]);
      }
      Bf[ks][nt] = f;
    }

  __syncthreads();
  const int cnt = cntLds;

  float accT[4] = {0.f, 0.f, 0.f, 0.f};

  for (int base = 0; base < cnt; base += 64) {
    __syncthreads();  // protect jpc/cpk from previous chunk's readers
    if (wid == 0) {
      int pg = base + lane;
      int jp = (pg < cnt) ? (int)Lst[pg] : (int)Lst[0];
      jpc[lane] = (short)jp;
      float c0 = corr[(i * NN + jp) * 2 + 0];
      float c1 = corr[(i * NN + jp) * 2 + 1];
      float var = c0 * c0 * e00 + c1 * c1 * e11 + ebb +
                  2.f * (c0 * c1 * e01 + c0 * e0b + c1 * e1b);
      float4v v;
      v[0] = c0;
      v[1] = c1;
      v[2] = rsqrtf(var + EPSF);
      v[3] = 0.f;
      cpk[lane] = v;
    }
    __syncthreads();

    // Phase b: each wave writes its own 16 R rows (pairs wid*16 .. +15).
    float4v myc = cpk[wid * 16 + nl];
#pragma unroll
    for (int q = 0; q < 16; ++q) {
      int p = wid * 16 + q;
      float c0 = __shfl(myc[0], q);
      float c1 = __shfl(myc[1], q);
      float iv = __shfl(myc[2], q);
      float s3 = fmaf(c0, gw0, fmaf(c1, gw1, gbh));  // g_r * (raw - u)
      float r = fmaxf(0.f, fmaf(iv, s3, pber));
      Rt[p * 72 + lane] = f2bf(r);
    }

    // Phase c: MFMA (reads only this wave's own rows; same-wave DS order OK).
    short8 a0, a1;
    __builtin_memcpy(&a0, &Rt[(wid * 16 + nl) * 72 + quad * 8], 16);
    __builtin_memcpy(&a1, &Rt[(wid * 16 + nl) * 72 + 32 + quad * 8], 16);
    float4v acc[4];
#pragma unroll
    for (int nt = 0; nt < 4; ++nt) {
      float4v z = {0.f, 0.f, 0.f, 0.f};
      z = __builtin_amdgcn_mfma_f32_16x16x32_bf16(a0, Bf[0][nt], z, 0, 0, 0);
      z = __builtin_amdgcn_mfma_f32_16x16x32_bf16(a1, Bf[1][nt], z, 0, 0, 0);
      acc[nt] = z;
    }

    // Epilogue: y = z + A_pre_i + B_pre_j; LN over d; sigmoid; acc gate*h[j].
    int jpr[4];
    float pv[4];
#pragma unroll
    for (int rr = 0; rr < 4; ++rr) {
      int pl = wid * 16 + quad * 4 + rr;  // C layout: m = quad*4 + reg
      jpr[rr] = (int)jpc[pl];
      pv[rr] = (base + pl < cnt) ? 1.f : 0.f;
    }
    float y[4][4];
#pragma unroll
    for (int nt = 0; nt < 4; ++nt)
#pragma unroll
      for (int rr = 0; rr < 4; ++rr)
        y[nt][rr] = acc[nt][rr] + pre4[nt] + B_pre[jpr[rr] * DD + nt * 16 + nl];
#pragma unroll
    for (int rr = 0; rr < 4; ++rr) {
      float s = y[0][rr] + y[1][rr] + y[2][rr] + y[3][rr];
      float qq = y[0][rr] * y[0][rr] + y[1][rr] * y[1][rr] +
                 y[2][rr] * y[2][rr] + y[3][rr] * y[3][rr];
#pragma unroll
      for (int m = 1; m < 16; m <<= 1) {
        s += __shfl_xor(s, m);
        qq += __shfl_xor(qq, m);
      }
      float u = s * (1.f / DD);
      float var = qq * (1.f / DD) - u * u;
      float inv = rsqrtf(var + EPSF);
      int jj = jpr[rr];
#pragma unroll
      for (int nt = 0; nt < 4; ++nt) {
        float g = fmaf(gg4[nt], (y[nt][rr] - u) * inv, beg4[nt]);
        float gate = __frcp_rn(1.f + __expf(-g));
        float hval = hidden[jj * DD + nt * 16 + nl];
        accT[nt] = fmaf(gate * pv[rr], hval, accT[nt]);
      }
    }
  }

  // Reduce partial sums: over quads, then over waves via LDS.
#pragma unroll
  for (int nt = 0; nt < 4; ++nt) {
    accT[nt] += __shfl_xor(accT[nt], 16);
    accT[nt] += __shfl_xor(accT[nt], 32);
  }
  if (lane < 16) {
#pragma unroll
    for (int nt = 0; nt < 4; ++nt) red[wid * 64 + nt * 16 + lane] = accT[nt];
  }
  __syncthreads();

  if (tid < 64) {  // wave 0 only
    int d = tid;
    float hs = red[d] + red[64 + d] + red[128 + d] + red[192 + d];
    float tta = fmaxf(bea[0], 0.f);
    float wgt = (tta > 0.f && cnt > 0) ? (1.f / (float)cnt) : (1.f / (float)NN);
    hs *= wgt;  // H_sum[i][d]
    // dot with W_w column d
    float dotv = bw[d];
#pragma unroll 8
    for (int k = 0; k < DD; ++k) {
      float hk = __shfl(hs, k);
      dotv = fmaf(hk, Ww[k * DD + d], dotv);
    }
    float s = dotv, qq = dotv * dotv;
#pragma unroll
    for (int m = 1; m < 64; m <<= 1) {
      s += __shfl_xor(s, m);
      qq += __shfl_xor(qq, m);
    }
    float u = s * (1.f / DD);
    float var = qq * (1.f / DD) - u * u;
    float inv = rsqrtf(var + EPSF);
    float val = fmaxf(0.f, fmaf(gw[d], (dotv - u) * inv, bew[d]));
    float Cv = val + cn[i * DD + d];
    float Ho = hidden[i * DD + d] + tanhf(Cv);
    out[i * DD + d] = Ho;
    out[NN * DD + i * DD + d] = Cv;
  }
}

extern "C" void kernel_launch(void* const* d_in, const int* in_sizes, int n_in,
                              void* d_out, int out_size, void* d_ws,
                              size_t ws_size, hipStream_t stream) {
  const float* corr = (const float*)d_in[0];
  const int* nei = (const int*)d_in[1];
  // d_in[2] nei_num: unused by the reference math
  const float* hidden = (const float*)d_in[3];
  const float* cn = (const float*)d_in[4];
  const float* Wr = (const float*)d_in[5];
  const float* br = (const float*)d_in[6];
  const float* gr = (const float*)d_in[7];
  const float* ber = (const float*)d_in[8];
  const float* Wg = (const float*)d_in[9];
  const float* bg = (const float*)d_in[10];
  const float* gg = (const float*)d_in[11];
  const float* beg = (const float*)d_in[12];
  // d_in[13..15] W_a/b_a/g_a: cancel analytically (LN over size-1 axis)
  const float* bea = (const float*)d_in[16];
  const float* Ww = (const float*)d_in[17];
  const float* bw = (const float*)d_in[18];
  const float* gw = (const float*)d_in[19];
  const float* bew = (const float*)d_in[20];
  float* out = (float*)d_out;

  float* ws = (float*)d_ws;
  float* A_pre = ws;                 // NN*DD
  float* B_pre = ws + NN * DD;       // NN*DD
  float* w0h = ws + 2 * NN * DD;     // 64
  float* w1h = w0h + 64;             // 64
  float* bh = w0h + 128;             // 64
  float* evec = w0h + 192;           // 6

  prep_kernel<<<NN + 1, 64, 0, stream>>>(hidden, Wg, bg, Wr, br, A_pre, B_pre,
                                         w0h, w1h, bh, evec);
  gatraj_main<<<NN, 256, 0, stream>>>(corr, nei, hidden, cn, gr, ber, Wg, gg,
                                      beg, bea, Ww, bw, gw, bew, A_pre, B_pre,
                                      w0h, w1h, bh, evec, out);
}